// Round 10
// baseline (413.316 us; speedup 1.0000x reference)
//
#include <hip/hip_runtime.h>
#include <hip/hip_bf16.h>

typedef __attribute__((ext_vector_type(8))) short bf16x8;
typedef __attribute__((ext_vector_type(4))) float f32x4;
typedef __attribute__((ext_vector_type(2))) float f32x2;

#define EPB 2048         // edges per partition block
#define BUCKET_BITS 8
#define BUCKET_SIZE 256  // nodes per bucket
#define MAXBUCK 512

static __device__ __forceinline__ unsigned short f2bf(float f) {
    union { float f; unsigned u; } v; v.f = f;
    unsigned r = v.u + 0x7FFF + ((v.u >> 16) & 1);
    return (unsigned short)(r >> 16);
}
static __device__ __forceinline__ float asf(unsigned u) {
    union { unsigned u; float f; } v; v.u = u;
    return v.f;
}
static __device__ __forceinline__ f32x2 cvt2(unsigned u) {
    f32x2 r;
    r.x = asf(u << 16);
    r.y = asf(u & 0xFFFF0000u);
    return r;
}

// ================= device helpers =================

// gather-aggregate one node (wave of 64 lanes), relu + bf16 pack
static __device__ __forceinline__ void dev_agg(int node, int L,
                                               const unsigned short* __restrict__ xr,
                                               const unsigned short* __restrict__ accbf,
                                               const int* __restrict__ off_,
                                               const int* __restrict__ deg,
                                               const int* __restrict__ csr_src,
                                               unsigned short* __restrict__ out) {
    int g = L >> 4;
    int f = L & 15;
    int o = off_[node];
    int d = deg[node];
    uint4 arow = (uint4){0, 0, 0, 0};
    if (g == 0) arow = *(const uint4*)(accbf + (size_t)node * 128 + f * 8);

    const int* ip = csr_src + o + g;
    const unsigned short* xrf = xr + f * 8;

    f32x2 a0 = (f32x2){0.f, 0.f}, a1 = (f32x2){0.f, 0.f};
    f32x2 a2 = (f32x2){0.f, 0.f}, a3 = (f32x2){0.f, 0.f};

    int d4 = d & ~3;
#pragma unroll 4
    for (int k = 0; k < d4; k += 4) {
        int s = ip[k];  // group-uniform -> HW broadcast
        uint4 p = *(const uint4*)(xrf + (size_t)s * 128);
        a0 += cvt2(p.x);
        a1 += cvt2(p.y);
        a2 += cvt2(p.z);
        a3 += cvt2(p.w);
    }
    if (d4 + g < d) {
        int s = ip[d4];
        uint4 p = *(const uint4*)(xrf + (size_t)s * 128);
        a0 += cvt2(p.x);
        a1 += cvt2(p.y);
        a2 += cvt2(p.z);
        a3 += cvt2(p.w);
    }
    a0.x += __shfl_xor(a0.x, 16, 64); a0.y += __shfl_xor(a0.y, 16, 64);
    a1.x += __shfl_xor(a1.x, 16, 64); a1.y += __shfl_xor(a1.y, 16, 64);
    a2.x += __shfl_xor(a2.x, 16, 64); a2.y += __shfl_xor(a2.y, 16, 64);
    a3.x += __shfl_xor(a3.x, 16, 64); a3.y += __shfl_xor(a3.y, 16, 64);
    a0.x += __shfl_xor(a0.x, 32, 64); a0.y += __shfl_xor(a0.y, 32, 64);
    a1.x += __shfl_xor(a1.x, 32, 64); a1.y += __shfl_xor(a1.y, 32, 64);
    a2.x += __shfl_xor(a2.x, 32, 64); a2.y += __shfl_xor(a2.y, 32, 64);
    a3.x += __shfl_xor(a3.x, 32, 64); a3.y += __shfl_xor(a3.y, 32, 64);

    if (g == 0) {
        uint4 wv;
        wv.x = ((unsigned)f2bf(fmaxf(asf(arow.x & 0xFFFF0000u) + a0.y, 0.f)) << 16)
             | f2bf(fmaxf(asf(arow.x << 16) + a0.x, 0.f));
        wv.y = ((unsigned)f2bf(fmaxf(asf(arow.y & 0xFFFF0000u) + a1.y, 0.f)) << 16)
             | f2bf(fmaxf(asf(arow.y << 16) + a1.x, 0.f));
        wv.z = ((unsigned)f2bf(fmaxf(asf(arow.z & 0xFFFF0000u) + a2.y, 0.f)) << 16)
             | f2bf(fmaxf(asf(arow.z << 16) + a2.x, 0.f));
        wv.w = ((unsigned)f2bf(fmaxf(asf(arow.w & 0xFFFF0000u) + a3.y, 0.f)) << 16)
             | f2bf(fmaxf(asf(arow.w << 16) + a3.x, 0.f));
        *(uint4*)(out + (size_t)node * 128 + f * 8) = wv;
    }
}

// one 16-row layer-GEMM tile (bf16 A, B from given pointer - global or LDS)
static __device__ __forceinline__ void dev_gemm_tile(int tile, int L,
                                                     const unsigned short* __restrict__ Abf,
                                                     const unsigned short* Bsrc,
                                                     const float* __restrict__ bias,
                                                     unsigned short* __restrict__ xrO,
                                                     unsigned short* __restrict__ accO, int N) {
    int r0 = tile * 16;
    if (r0 >= N) return;
    int arow = r0 + (L & 15);
    const bf16x8* Bptr = ((const bf16x8*)Bsrc) + L;
    f32x4 acc[16];
#pragma unroll
    for (int i = 0; i < 16; i++) acc[i] = (f32x4){0.f, 0.f, 0.f, 0.f};
#pragma unroll
    for (int kt = 0; kt < 4; kt++) {
        bf16x8 a = *((const bf16x8*)(Abf + (size_t)arow * 128 + ((L >> 4) * 8) + kt * 32));
#pragma unroll
        for (int ct = 0; ct < 16; ct++) {
            bf16x8 b = Bptr[(kt * 16 + ct) * 64];
            acc[ct] = __builtin_amdgcn_mfma_f32_16x16x32_bf16(a, b, acc[ct], 0, 0, 0);
        }
    }
    int rbase = r0 + (L >> 4) * 4;
    int cl = L & 15;
#pragma unroll
    for (int ct = 0; ct < 16; ct++) {
        int col = ct * 16 + cl;
#pragma unroll
        for (int r = 0; r < 4; r++) {
            int row = rbase + r;
            float v = acc[ct][r];
            if (col < 128)
                xrO[(size_t)row * 128 + col] = f2bf(v);
            else
                accO[(size_t)row * 128 + (col - 128)] = f2bf(v + bias[col - 128]);
        }
    }
}

// one 16-row final-GEMM + log_softmax tile (B from given pointer)
static __device__ __forceinline__ void dev_final_tile(int tile, int L,
                                                      const unsigned short* __restrict__ x1bf,
                                                      const unsigned short* __restrict__ x2bf,
                                                      const unsigned short* Bsrc,
                                                      const float* __restrict__ blin,
                                                      float* __restrict__ out, int N) {
    int r0 = tile * 16;
    if (r0 >= N) return;
    int arow = r0 + (L & 15);
    f32x4 acc[3];
#pragma unroll
    for (int i = 0; i < 3; i++) acc[i] = (f32x4){0.f, 0.f, 0.f, 0.f};
#pragma unroll
    for (int kt = 0; kt < 8; kt++) {
        const unsigned short* Ab = (kt < 4) ? x1bf : x2bf;
        int kk = (kt & 3) * 32 + ((L >> 4) * 8);
        bf16x8 a = *((const bf16x8*)(Ab + (size_t)arow * 128 + kk));
#pragma unroll
        for (int ct = 0; ct < 3; ct++) {
            bf16x8 b = ((const bf16x8*)Bsrc)[(kt * 3 + ct) * 64 + L];
            acc[ct] = __builtin_amdgcn_mfma_f32_16x16x32_bf16(a, b, acc[ct], 0, 0, 0);
        }
    }
    int rbase = r0 + (L >> 4) * 4;
    int cl = L & 15;
    float b0 = blin[cl], b1 = blin[16 + cl];
    float b2 = (cl < 8) ? blin[32 + cl] : 0.f;
#pragma unroll
    for (int r = 0; r < 4; r++) {
        int row = rbase + r;
        float v0 = acc[0][r] + b0;
        float v1 = acc[1][r] + b1;
        float v2 = (cl < 8) ? (acc[2][r] + b2) : -__builtin_inff();
        float m = fmaxf(fmaxf(v0, v1), v2);
#pragma unroll
        for (int off = 8; off >= 1; off >>= 1) m = fmaxf(m, __shfl_xor(m, off, 64));
        float e = __expf(v0 - m) + __expf(v1 - m) + ((cl < 8) ? __expf(v2 - m) : 0.f);
#pragma unroll
        for (int off = 8; off >= 1; off >>= 1) e += __shfl_xor(e, off, 64);
        float ls = m + __logf(e);
        float* op = out + (size_t)row * 40;
        op[cl] = v0 - ls;
        op[16 + cl] = v1 - ls;
        if (cl < 8) op[32 + cl] = v2 - ls;
    }
}

// ================= K1: prep — weight swizzles + edge histogram + bucket totals =================
__global__ __launch_bounds__(256) void prep(const float* __restrict__ Wrel1,
                                            const float* __restrict__ Wroot1,
                                            const float* __restrict__ Wrel2,
                                            const float* __restrict__ Wroot2,
                                            const float* __restrict__ Wlin,
                                            const int* __restrict__ dst,
                                            unsigned short* __restrict__ bsw1,
                                            unsigned short* __restrict__ bsw2,
                                            unsigned short* __restrict__ bswL,
                                            int* __restrict__ hist,
                                            int* __restrict__ bucketTot,
                                            int E, int nblk, int nbuck) {
    __shared__ int h[MAXBUCK];
    int blk = blockIdx.x, t = threadIdx.x;
    if (blk < 256) {
        const float* Wrel  = (blk < 128) ? Wrel1 : Wrel2;
        const float* Wroot = (blk < 128) ? Wroot1 : Wroot2;
        unsigned short* bsw = (blk < 128) ? bsw1 : bsw2;
        int idx = (blk & 127) * 256 + t;  // 32768 total
        int j = idx & 7, L = (idx >> 3) & 63, ct = (idx >> 9) & 15, kt = idx >> 13;
        int k = kt * 32 + ((L >> 4) * 8) + j;
        int c = ct * 16 + (L & 15);
        float v = (c < 128) ? Wrel[k * 128 + c] : Wroot[k * 128 + (c - 128)];
        bsw[idx] = f2bf(v);
    } else if (blk < 304) {
        int idx = (blk - 256) * 256 + t;  // 12288 total
        int tt = idx;
        int j = tt & 7; tt >>= 3;
        int L = tt & 63; tt >>= 6;
        int ct = tt % 3;
        int kt = tt / 3;
        int k = kt * 32 + ((L >> 4) * 8) + j;
        int c = ct * 16 + (L & 15);
        float v = (c < 40) ? Wlin[k * 40 + c] : 0.f;
        bswL[idx] = f2bf(v);
    } else {
        int hb = blk - 304;
        for (int i = t; i < MAXBUCK; i += 256) h[i] = 0;
        __syncthreads();
        int e0 = hb * EPB;
#pragma unroll
        for (int it = 0; it < EPB / 256; it++) {
            int e = e0 + it * 256 + t;
            if (e < E) atomicAdd(&h[dst[e] >> BUCKET_BITS], 1);
        }
        __syncthreads();
        for (int i = t; i < nbuck; i += 256) {
            int v = h[i];
            hist[i * nblk + hb] = v;
            if (v) atomicAdd(&bucketTot[i], v);
        }
    }
}

// ================= K2: merged scans — each block computes all bucket bases, scans its row =================
__global__ __launch_bounds__(256) void scan2(int* __restrict__ hist,
                                             const int* __restrict__ bucketTot,
                                             int* __restrict__ bucketBase,
                                             int nblk, int nbuck, int E) {
    __shared__ int s[256];
    __shared__ int bases[MAXBUCK];
    int b = blockIdx.x, t = threadIdx.x;
    int e0 = (2 * t < nbuck) ? bucketTot[2 * t] : 0;
    int e1 = (2 * t + 1 < nbuck) ? bucketTot[2 * t + 1] : 0;
    int ps = e0 + e1;
    s[t] = ps; __syncthreads();
#pragma unroll
    for (int o = 1; o < 256; o <<= 1) {
        int x = (t >= o) ? s[t - o] : 0;
        __syncthreads();
        s[t] += x; __syncthreads();
    }
    int pbase = s[t] - ps;
    bases[2 * t] = pbase;
    bases[2 * t + 1] = pbase + e0;
    __syncthreads();
    int base_b = bases[b];
    if (t == 0) {
        bucketBase[b] = base_b;
        if (b == 0) bucketBase[nbuck] = E;
    }
    // scan own hist row with carry
    int carryv = base_b;
    for (int start = 0; start < nblk; start += 256) {
        int i = start + t;
        int v = (i < nblk) ? hist[b * nblk + i] : 0;
        __syncthreads();
        s[t] = v; __syncthreads();
#pragma unroll
        for (int o = 1; o < 256; o <<= 1) {
            int x = (t >= o) ? s[t - o] : 0;
            __syncthreads();
            s[t] += x; __syncthreads();
        }
        int excl = s[t] - v + carryv;
        if (i < nblk) hist[b * nblk + i] = excl;
        carryv += s[255];
    }
}

// ================= K3: per-chunk LDS counting sort -> bucket-sorted packed records =================
__global__ __launch_bounds__(256) void edge_part(const int* __restrict__ src,
                                                 const int* __restrict__ dst,
                                                 const int* __restrict__ hist,  // block bases
                                                 int* __restrict__ part,
                                                 int E, int nblk, int nbuck) {
    __shared__ int hcnt[MAXBUCK];
    __shared__ int lstart[MAXBUCK];
    __shared__ int cur[MAXBUCK];
    __shared__ int gbase[MAXBUCK];
    __shared__ int s2[256];
    __shared__ int sdst[EPB];  // 8 KB
    __shared__ int ssrc[EPB];  // 8 KB
    int t = threadIdx.x, blk = blockIdx.x;
    int e0 = blk * EPB;
    int cnt = E - e0; if (cnt > EPB) cnt = EPB;
    for (int i = t; i < MAXBUCK; i += 256) hcnt[i] = 0;
    for (int i = t; i < nbuck; i += 256) gbase[i] = hist[i * nblk + blk];
    __syncthreads();
    int myd[EPB / 256], mys[EPB / 256];
#pragma unroll
    for (int it = 0; it < EPB / 256; it++) {
        int i = it * 256 + t;
        if (i < cnt) {
            myd[it] = dst[e0 + i];
            mys[it] = src[e0 + i];
            atomicAdd(&hcnt[myd[it] >> BUCKET_BITS], 1);
        }
    }
    __syncthreads();
    int p0 = hcnt[2 * t], p1 = hcnt[2 * t + 1];
    int ps = p0 + p1;
    s2[t] = ps; __syncthreads();
#pragma unroll
    for (int o = 1; o < 256; o <<= 1) {
        int x = (t >= o) ? s2[t - o] : 0;
        __syncthreads();
        s2[t] += x; __syncthreads();
    }
    int pbase = s2[t] - ps;
    lstart[2 * t] = pbase; lstart[2 * t + 1] = pbase + p0;
    cur[2 * t] = 0; cur[2 * t + 1] = 0;
    __syncthreads();
#pragma unroll
    for (int it = 0; it < EPB / 256; it++) {
        int i = it * 256 + t;
        if (i < cnt) {
            int b = myd[it] >> BUCKET_BITS;
            int p = lstart[b] + atomicAdd(&cur[b], 1);
            sdst[p] = myd[it];
            ssrc[p] = mys[it];
        }
    }
    __syncthreads();
    for (int i = t; i < cnt; i += 256) {
        int d = sdst[i], s = ssrc[i];
        int b = d >> BUCKET_BITS;
        part[gbase[b] + (i - lstart[b])] = ((d & (BUCKET_SIZE - 1)) << 17) | s;
    }
}

// ================= K4: csr_finalize (blocks 0..nbuck-1) + layer-1 GEMM (rest) =================
__global__ __launch_bounds__(256) void csrfin_gemm1(const int* __restrict__ part,
                                                    const int* __restrict__ bucketBase,
                                                    int* __restrict__ off_,
                                                    int* __restrict__ deg_,
                                                    int* __restrict__ csr_src,
                                                    const float* __restrict__ x,
                                                    const unsigned short* __restrict__ Bsw,
                                                    const float* __restrict__ bias,
                                                    unsigned short* __restrict__ xr,
                                                    unsigned short* __restrict__ accbf,
                                                    int N, int nbuck) {
    __shared__ int cur[BUCKET_SIZE];
    __shared__ int h[BUCKET_SIZE];
    __shared__ int tsum[256];
    int t = threadIdx.x;
    if (blockIdx.x < (unsigned)nbuck) {
        int b = blockIdx.x;
        int lo = bucketBase[b], hi = bucketBase[b + 1];
        int n0 = b * BUCKET_SIZE;
        h[t] = 0;
        __syncthreads();
        for (int i = lo + t; i < hi; i += 256) atomicAdd(&h[part[i] >> 17], 1);
        __syncthreads();
        int hv = h[t];
        tsum[t] = hv;
        __syncthreads();
#pragma unroll
        for (int o = 1; o < 256; o <<= 1) {
            int xx = (t >= o) ? tsum[t - o] : 0;
            __syncthreads();
            tsum[t] += xx;
            __syncthreads();
        }
        int st = tsum[t] - hv;
        cur[t] = st;
        int node = n0 + t;
        if (node < N) { off_[node] = lo + st; deg_[node] = hv; }
        __syncthreads();
        for (int i = lo + t; i < hi; i += 256) {
            int rec = part[i];
            int p = atomicAdd(&cur[rec >> 17], 1);
            csr_src[lo + p] = rec & 0x1FFFF;
        }
    } else {
        int wid = (blockIdx.x - nbuck) * 4 + (t >> 6);
        int L = t & 63;
        int r0 = wid * 16;
        if (r0 >= N) return;
        int arow = r0 + (L & 15);
        const bf16x8* Bptr = ((const bf16x8*)Bsw) + L;
        f32x4 acc[16];
#pragma unroll
        for (int i = 0; i < 16; i++) acc[i] = (f32x4){0.f, 0.f, 0.f, 0.f};
#pragma unroll
        for (int kt = 0; kt < 4; kt++) {
            const float* Arow = x + (size_t)arow * 128 + ((L >> 4) * 8) + kt * 32;
            float4 a0 = *(const float4*)Arow;
            float4 a1 = *(const float4*)(Arow + 4);
            bf16x8 a;
            a[0] = (short)f2bf(a0.x); a[1] = (short)f2bf(a0.y);
            a[2] = (short)f2bf(a0.z); a[3] = (short)f2bf(a0.w);
            a[4] = (short)f2bf(a1.x); a[5] = (short)f2bf(a1.y);
            a[6] = (short)f2bf(a1.z); a[7] = (short)f2bf(a1.w);
#pragma unroll
            for (int ct = 0; ct < 16; ct++) {
                bf16x8 b = Bptr[(kt * 16 + ct) * 64];
                acc[ct] = __builtin_amdgcn_mfma_f32_16x16x32_bf16(a, b, acc[ct], 0, 0, 0);
            }
        }
        int rbase = r0 + (L >> 4) * 4;
        int cl = L & 15;
#pragma unroll
        for (int ct = 0; ct < 16; ct++) {
            int col = ct * 16 + cl;
#pragma unroll
            for (int r = 0; r < 4; r++) {
                int row = rbase + r;
                float v = acc[ct][r];
                if (col < 128)
                    xr[(size_t)row * 128 + col] = f2bf(v);
                else
                    accbf[(size_t)row * 128 + (col - 128)] = f2bf(v + bias[col - 128]);
            }
        }
    }
}

// ================= K5/K8: plain aggregation over a node range =================
__global__ __launch_bounds__(256) void agg_k(const unsigned short* __restrict__ xr,
                                             const unsigned short* __restrict__ accbf,
                                             const int* __restrict__ off_,
                                             const int* __restrict__ deg,
                                             const int* __restrict__ csr_src,
                                             unsigned short* __restrict__ out,
                                             int node0, int nNodes) {
    int rel = blockIdx.x * 4 + (threadIdx.x >> 6);
    if (rel >= nNodes) return;
    dev_agg(node0 + rel, threadIdx.x & 63, xr, accbf, off_, deg, csr_src, out);
}

// ================= K6: agg (node range B) + layer-GEMM (tile range A, B from L2) =================
__global__ __launch_bounds__(256) void agg_gemm(const unsigned short* __restrict__ xr,
                                                const unsigned short* __restrict__ accbf,
                                                const int* __restrict__ off_,
                                                const int* __restrict__ deg,
                                                const int* __restrict__ csr_src,
                                                unsigned short* __restrict__ aggOut,
                                                int aggNode0, int aggNodes, int aggBlocks,
                                                const unsigned short* __restrict__ Abf,
                                                const unsigned short* __restrict__ Bsw,
                                                const float* __restrict__ bias,
                                                unsigned short* __restrict__ xrO,
                                                unsigned short* __restrict__ accO,
                                                int nTilesA, int N) {
    int t = threadIdx.x;
    if ((int)blockIdx.x < aggBlocks) {
        int rel = blockIdx.x * 4 + (t >> 6);
        if (rel < aggNodes) dev_agg(aggNode0 + rel, t & 63, xr, accbf, off_, deg, csr_src, aggOut);
    } else {
        int wid = (blockIdx.x - aggBlocks) * 4 + (t >> 6);
        if (wid < nTilesA) dev_gemm_tile(wid, t & 63, Abf, Bsw, bias, xrO, accO, N);
    }
}

// ================= K9: agg (node range B) + final-GEMM+softmax (tile range A) =================
__global__ __launch_bounds__(256) void agg_final(const unsigned short* __restrict__ xr,
                                                 const unsigned short* __restrict__ accbf,
                                                 const int* __restrict__ off_,
                                                 const int* __restrict__ deg,
                                                 const int* __restrict__ csr_src,
                                                 unsigned short* __restrict__ aggOut,
                                                 int aggNode0, int aggNodes, int aggBlocks,
                                                 const unsigned short* __restrict__ x1bf,
                                                 const unsigned short* __restrict__ x2bf,
                                                 const unsigned short* __restrict__ bswL,
                                                 const float* __restrict__ blin,
                                                 float* __restrict__ out,
                                                 int nTilesA, int N) {
    int t = threadIdx.x;
    if ((int)blockIdx.x < aggBlocks) {
        int rel = blockIdx.x * 4 + (t >> 6);
        if (rel < aggNodes) dev_agg(aggNode0 + rel, t & 63, xr, accbf, off_, deg, csr_src, aggOut);
    } else {
        int wid = (blockIdx.x - aggBlocks) * 4 + (t >> 6);
        if (wid < nTilesA) dev_final_tile(wid, t & 63, x1bf, x2bf, bswL, blin, out, N);
    }
}

// ================= K7: layer-GEMM tile range [tile0, tileEnd), B staged in LDS =================
__global__ __launch_bounds__(256) void gemm_layer_rng(const unsigned short* __restrict__ Abf,
                                                      const unsigned short* __restrict__ Bsw,
                                                      const float* __restrict__ bias,
                                                      unsigned short* __restrict__ xrO,
                                                      unsigned short* __restrict__ accO,
                                                      int tile0, int tileEnd, int N) {
    __shared__ unsigned short Bs[32768];  // 64 KB
    int t = threadIdx.x;
    {
        uint4* d4 = (uint4*)Bs;
        const uint4* s4 = (const uint4*)Bsw;
#pragma unroll
        for (int i = 0; i < 16; i++) d4[t + i * 256] = s4[t + i * 256];
    }
    __syncthreads();
    int w = t >> 6, L = t & 63;
    for (int tile = tile0 + blockIdx.x * 4 + w; tile < tileEnd; tile += gridDim.x * 4)
        dev_gemm_tile(tile, L, Abf, Bs, bias, xrO, accO, N);
}

// ================= K10: final tile range [tile0, tileEnd), B staged in LDS =================
__global__ __launch_bounds__(256) void final_rng(const unsigned short* __restrict__ x1bf,
                                                 const unsigned short* __restrict__ x2bf,
                                                 const unsigned short* __restrict__ bswL,
                                                 const float* __restrict__ blin,
                                                 float* __restrict__ out,
                                                 int tile0, int tileEnd, int N) {
    __shared__ unsigned short Bs[12288];  // 24 KB
    int t = threadIdx.x;
    {
        uint4* d4 = (uint4*)Bs;
        const uint4* s4 = (const uint4*)bswL;
#pragma unroll
        for (int i = 0; i < 6; i++) d4[t + i * 256] = s4[t + i * 256];
    }
    __syncthreads();
    int w = t >> 6, L = t & 63;
    for (int tile = tile0 + blockIdx.x * 4 + w; tile < tileEnd; tile += gridDim.x * 4)
        dev_final_tile(tile, L, x1bf, x2bf, Bs, blin, out, N);
}

extern "C" void kernel_launch(void* const* d_in, const int* in_sizes, int n_in,
                              void* d_out, int out_size, void* d_ws, size_t ws_size,
                              hipStream_t stream) {
    const float* x      = (const float*)d_in[0];
    const int*   edge   = (const int*)d_in[1];
    const float* Wrel1  = (const float*)d_in[2];
    const float* brel1  = (const float*)d_in[3];
    const float* Wroot1 = (const float*)d_in[4];
    const float* Wrel2  = (const float*)d_in[5];
    const float* brel2  = (const float*)d_in[6];
    const float* Wroot2 = (const float*)d_in[7];
    const float* Wlin   = (const float*)d_in[8];
    const float* blin   = (const float*)d_in[9];

    const int N = in_sizes[0] / 128;
    const int E = in_sizes[1] / 2;
    const int* src = edge;
    const int* dst = edge + E;

    const int nblk  = (E + EPB - 1) / EPB;                    // 782
    const int nbuck = (N + BUCKET_SIZE - 1) / BUCKET_SIZE;    // 391

    char* ws = (char*)d_ws;
    size_t off = 0;
    auto alloc = [&](size_t bytes) -> void* {
        void* p = ws + off;
        off += (bytes + 255) & ~(size_t)255;
        return p;
    };
    unsigned short* x1bf = (unsigned short*)alloc((size_t)N * 128 * 2);
    unsigned short* x2bf = (unsigned short*)alloc((size_t)N * 128 * 2);
    unsigned short* xr1  = (unsigned short*)alloc((size_t)N * 128 * 2);
    unsigned short* acc1 = (unsigned short*)alloc((size_t)N * 128 * 2);
    unsigned short* xr2  = (unsigned short*)alloc((size_t)N * 128 * 2);
    unsigned short* acc2 = (unsigned short*)alloc((size_t)N * 128 * 2);
    unsigned short* bsw1 = (unsigned short*)alloc(32768 * 2);
    unsigned short* bsw2 = (unsigned short*)alloc(32768 * 2);
    unsigned short* bswL = (unsigned short*)alloc(12288 * 2);
    int* hist       = (int*)alloc((size_t)nbuck * nblk * 4);
    int* bucketTot  = (int*)alloc((size_t)nbuck * 4);
    int* bucketBase = (int*)alloc((size_t)(nbuck + 1) * 4);
    int* part       = (int*)alloc((size_t)E * 4);
    int* csr_src    = (int*)alloc((size_t)E * 4);
    int* off_       = (int*)alloc((size_t)N * 4);
    int* deg_       = (int*)alloc((size_t)N * 4);

    const int tilesTotal = (N + 15) / 16;                 // 6250
    const int gemmBlocksFull = (tilesTotal + 3) / 4;      // 1563
    const int halfN = ((N / 2) / 16) * 16;                // 50000 (multiple of 16)
    const int nodesB = N - halfN;
    const int aggBlocksA = (halfN + 3) / 4;               // 12500
    const int aggBlocksB = (nodesB + 3) / 4;              // 12500
    const int tilesA = halfN / 16;                        // 3125
    const int gemmABlocks = (tilesA + 3) / 4;             // 782

    // K0: zero bucket totals
    hipMemsetAsync(bucketTot, 0, (size_t)nbuck * 4, stream);
    // K1: weight swizzles + edge histogram + bucket totals
    prep<<<304 + nblk, 256, 0, stream>>>(Wrel1, Wroot1, Wrel2, Wroot2, Wlin, dst,
                                         bsw1, bsw2, bswL, hist, bucketTot, E, nblk, nbuck);
    // K2: merged scans
    scan2<<<nbuck, 256, 0, stream>>>(hist, bucketTot, bucketBase, nblk, nbuck, E);
    // K3: partition
    edge_part<<<nblk, 256, 0, stream>>>(src, dst, hist, part, E, nblk, nbuck);
    // K4: CSR finalize + full layer-1 GEMM
    csrfin_gemm1<<<nbuck + gemmBlocksFull, 256, 0, stream>>>(part, bucketBase, off_, deg_, csr_src,
                                                             x, bsw1, brel1, xr1, acc1, N, nbuck);
    // K5: agg1 nodes [0, halfN)
    agg_k<<<aggBlocksA, 256, 0, stream>>>(xr1, acc1, off_, deg_, csr_src, x1bf, 0, halfN);
    // K6: agg1 nodes [halfN, N)  ||  gemm2 tiles [0, tilesA)  (writes xr2/acc2 — no overlap with agg reads)
    agg_gemm<<<aggBlocksB + gemmABlocks, 256, 0, stream>>>(xr1, acc1, off_, deg_, csr_src, x1bf,
                                                           halfN, nodesB, aggBlocksB,
                                                           x1bf, bsw2, brel2, xr2, acc2, tilesA, N);
    // K7: gemm2 tiles [tilesA, tilesTotal), B in LDS
    gemm_layer_rng<<<512, 256, 0, stream>>>(x1bf, bsw2, brel2, xr2, acc2, tilesA, tilesTotal, N);
    // K8: agg2 nodes [0, halfN)
    agg_k<<<aggBlocksA, 256, 0, stream>>>(xr2, acc2, off_, deg_, csr_src, x2bf, 0, halfN);
    // K9: agg2 nodes [halfN, N)  ||  final tiles [0, tilesA)
    agg_final<<<aggBlocksB + gemmABlocks, 256, 0, stream>>>(xr2, acc2, off_, deg_, csr_src, x2bf,
                                                            halfN, nodesB, aggBlocksB,
                                                            x1bf, x2bf, bswL, blin, (float*)d_out,
                                                            tilesA, N);
    // K10: final tiles [tilesA, tilesTotal), B in LDS
    final_rng<<<512, 256, 0, stream>>>(x1bf, x2bf, bswL, blin, (float*)d_out,
                                       tilesA, tilesTotal, N);
}